// Round 1
// baseline (118.647 us; speedup 1.0000x reference)
//
#include <hip/hip_runtime.h>

// Problem constants (from reference)
#define NB 4
#define S_IN 128
#define NC 64
#define S_OUT 32                      // 128 / 4 (two 2x pools)
#define OUT_CELLS (NB * S_OUT * S_OUT * S_OUT)   // 131072
#define OUT_ELEMS (OUT_CELLS * NC)               // 8388608 floats

// Monotonic float <-> unsigned mapping for atomicMax on floats.
__device__ __forceinline__ unsigned flip_f(float f) {
    unsigned u = __float_as_uint(f);
    return (u & 0x80000000u) ? ~u : (u | 0x80000000u);
}
__device__ __forceinline__ float unflip_f(unsigned u) {
    unsigned v = (u & 0x80000000u) ? (u & 0x7FFFFFFFu) : ~u;
    return __uint_as_float(v);
}

// Kernel 1: init accumulator (d_out reused as unsigned accumulator) to 0.
// 0 is strictly below flip of any finite float (min finite flip = 0x00800000
// for -FLT_MAX), so acc==0 <=> empty cell.
__global__ void init_kernel(uint4* __restrict__ out4, int n4) {
    int i = blockIdx.x * blockDim.x + threadIdx.x;
    int stride = gridDim.x * blockDim.x;
    uint4 z = make_uint4(0u, 0u, 0u, 0u);
    for (; i < n4; i += stride) out4[i] = z;
}

// Kernel 2: one 64-lane wave per point; lane = channel.
__global__ void scatter_kernel(const float* __restrict__ features,
                               const int4* __restrict__ coors,
                               unsigned* __restrict__ acc, int n_pts) {
    int gid = blockIdx.x * blockDim.x + threadIdx.x;
    int p = gid >> 6;           // wave id = point id
    int c = threadIdx.x & 63;   // lane = channel
    if (p >= n_pts) return;
    int4 co = coors[p];         // wave-uniform broadcast load
    int b = co.x;
    int z = co.y >> 2;
    int y = co.z >> 2;
    int x = co.w >> 2;
    int cell = ((b * S_OUT + z) * S_OUT + y) * S_OUT + x;
    float f = features[(size_t)p * NC + c];   // coalesced 256B per wave
    atomicMax(acc + (size_t)cell * NC + c, flip_f(f));
}

// Kernel 3: unflip in place; empty cells -> 0.
__global__ void finalize_kernel(unsigned* __restrict__ acc, int n) {
    int i = blockIdx.x * blockDim.x + threadIdx.x;
    int stride = gridDim.x * blockDim.x;
    for (; i < n; i += stride) {
        unsigned u = acc[i];
        float f = (u == 0u) ? 0.0f : unflip_f(u);
        ((float*)acc)[i] = f;
    }
}

extern "C" void kernel_launch(void* const* d_in, const int* in_sizes, int n_in,
                              void* d_out, int out_size, void* d_ws, size_t ws_size,
                              hipStream_t stream) {
    const float* features = (const float*)d_in[0];
    const int4*  coors    = (const int4*)d_in[1];
    int n_pts = in_sizes[0] / NC;   // 500000

    unsigned* acc = (unsigned*)d_out;

    // 1) init output accumulator to 0 sentinel
    {
        int n4 = OUT_ELEMS / 4;   // uint4 count
        int block = 256;
        int grid = 2048;
        init_kernel<<<grid, block, 0, stream>>>((uint4*)d_out, n4);
    }
    // 2) scatter atomic max
    {
        int block = 256;                     // 4 waves/block, 1 point/wave
        int waves_needed = n_pts;
        int grid = (waves_needed * 64 + block - 1) / block;
        scatter_kernel<<<grid, block, 0, stream>>>(features, coors, acc, n_pts);
    }
    // 3) finalize
    {
        int block = 256;
        int grid = 2048;
        finalize_kernel<<<grid, block, 0, stream>>>(acc, OUT_ELEMS);
    }
}

// Round 2
// 81.920 us; speedup vs baseline: 1.4483x; 1.4483x over previous
//
#include <hip/hip_runtime.h>

// Problem constants (from reference)
#define NB 4
#define S_OUT 32                                  // 128 / 4 (two 2x pools fused)
#define NC 64
#define OUT_CELLS (NB * S_OUT * S_OUT * S_OUT)    // 131072
#define OUT_ELEMS (OUT_CELLS * NC)                // 8388608 floats
#define CAP 32                                    // slots per cell (lambda=3.8)
#define OVF_CAP 16384

// ---------- gather path ----------

__global__ void fill_kernel(const int4* __restrict__ coors,
                            int* __restrict__ cnt,
                            int* __restrict__ list,
                            int* __restrict__ ovf_cnt,
                            int* __restrict__ ovf,
                            int n_pts) {
    int p = blockIdx.x * blockDim.x + threadIdx.x;
    if (p >= n_pts) return;
    int4 co = coors[p];
    int cell = ((co.x * S_OUT + (co.y >> 2)) * S_OUT + (co.z >> 2)) * S_OUT + (co.w >> 2);
    int slot = atomicAdd(&cnt[cell], 1);
    if (slot < CAP) {
        list[cell * CAP + slot] = p;
    } else {
        int o = atomicAdd(ovf_cnt, 1);
        if (o < OVF_CAP) ovf[o] = p;
    }
}

// One 64-lane wave per cell; lane = channel.
__global__ void gather_kernel(const float* __restrict__ features,
                              const int* __restrict__ cnt,
                              const int* __restrict__ list,
                              float* __restrict__ out) {
    int gid = blockIdx.x * blockDim.x + threadIdx.x;
    int cell = gid >> 6;
    int lane = threadIdx.x & 63;
    if (cell >= OUT_CELLS) return;
    int n = cnt[cell];
    int m = n < CAP ? n : CAP;
    // coalesced read of the cell's point list (lanes 0..31); consumed via shfl
    int pl = (lane < CAP) ? list[cell * CAP + lane] : 0;
    float acc = -INFINITY;
    for (int i = 0; i < m; ++i) {
        int p = __shfl(pl, i);
        float f = features[(size_t)p * NC + lane];   // 256B coalesced row
        acc = fmaxf(acc, f);
    }
    out[(size_t)cell * NC + lane] = (n > 0) ? acc : 0.0f;
}

__device__ __forceinline__ void atomicMaxFloat(float* addr, float val) {
    unsigned* ua = (unsigned*)addr;
    unsigned old = *ua;
    while (true) {
        float f = __uint_as_float(old);
        if (f >= val) break;
        unsigned assumed = old;
        old = atomicCAS(ua, assumed, __float_as_uint(val));
        if (old == assumed) break;
    }
}

// Folds overflow points (expected: zero) into the finished output.
__global__ void ovf_kernel(const float* __restrict__ features,
                           const int4* __restrict__ coors,
                           const int* __restrict__ ovf_cnt,
                           const int* __restrict__ ovf,
                           float* __restrict__ out) {
    int lane = threadIdx.x & 63;
    int wid = (blockIdx.x * blockDim.x + threadIdx.x) >> 6;
    int nw = (gridDim.x * blockDim.x) >> 6;
    int n = *ovf_cnt;
    if (n > OVF_CAP) n = OVF_CAP;
    for (int i = wid; i < n; i += nw) {
        int p = ovf[i];
        int4 co = coors[p];
        int cell = ((co.x * S_OUT + (co.y >> 2)) * S_OUT + (co.z >> 2)) * S_OUT + (co.w >> 2);
        atomicMaxFloat(&out[(size_t)cell * NC + lane], features[(size_t)p * NC + lane]);
    }
}

// ---------- fallback path (R1's working atomicMax scatter) ----------

__device__ __forceinline__ unsigned flip_f(float f) {
    unsigned u = __float_as_uint(f);
    return (u & 0x80000000u) ? ~u : (u | 0x80000000u);
}
__device__ __forceinline__ float unflip_f(unsigned u) {
    unsigned v = (u & 0x80000000u) ? (u & 0x7FFFFFFFu) : ~u;
    return __uint_as_float(v);
}

__global__ void init_kernel(uint4* __restrict__ out4, int n4) {
    int i = blockIdx.x * blockDim.x + threadIdx.x;
    int stride = gridDim.x * blockDim.x;
    uint4 z = make_uint4(0u, 0u, 0u, 0u);
    for (; i < n4; i += stride) out4[i] = z;
}

__global__ void scatter_kernel(const float* __restrict__ features,
                               const int4* __restrict__ coors,
                               unsigned* __restrict__ acc, int n_pts) {
    int gid = blockIdx.x * blockDim.x + threadIdx.x;
    int p = gid >> 6;
    int c = threadIdx.x & 63;
    if (p >= n_pts) return;
    int4 co = coors[p];
    int cell = ((co.x * S_OUT + (co.y >> 2)) * S_OUT + (co.z >> 2)) * S_OUT + (co.w >> 2);
    atomicMax(acc + (size_t)cell * NC + c, flip_f(features[(size_t)p * NC + c]));
}

__global__ void finalize_kernel(unsigned* __restrict__ acc, int n) {
    int i = blockIdx.x * blockDim.x + threadIdx.x;
    int stride = gridDim.x * blockDim.x;
    for (; i < n; i += stride) {
        unsigned u = acc[i];
        ((float*)acc)[i] = (u == 0u) ? 0.0f : unflip_f(u);
    }
}

extern "C" void kernel_launch(void* const* d_in, const int* in_sizes, int n_in,
                              void* d_out, int out_size, void* d_ws, size_t ws_size,
                              hipStream_t stream) {
    const float* features = (const float*)d_in[0];
    const int4*  coors    = (const int4*)d_in[1];
    int n_pts = in_sizes[0] / NC;   // 500000

    // workspace layout
    const size_t off_cnt  = 0;
    const size_t cnt_b    = (size_t)OUT_CELLS * 4;            // 524288
    const size_t off_ovfc = cnt_b;                             // 4B counter
    const size_t off_ovf  = off_ovfc + 256;
    const size_t off_list = off_ovf + (size_t)OVF_CAP * 4;
    const size_t need     = off_list + (size_t)OUT_CELLS * CAP * 4;

    if (ws_size >= need) {
        char* ws = (char*)d_ws;
        int* cnt     = (int*)(ws + off_cnt);
        int* ovf_cnt = (int*)(ws + off_ovfc);
        int* ovf     = (int*)(ws + off_ovf);
        int* list    = (int*)(ws + off_list);
        float* out   = (float*)d_out;

        // zero counters (cnt region + overflow counter)
        hipMemsetAsync(ws, 0, off_ovfc + 4, stream);

        // build per-cell point lists
        {
            int block = 256;
            int grid = (n_pts + block - 1) / block;
            fill_kernel<<<grid, block, 0, stream>>>(coors, cnt, list, ovf_cnt, ovf, n_pts);
        }
        // gather max per cell (writes every output element; no init needed)
        {
            int block = 256;                       // 4 cells per block
            int grid = (OUT_CELLS * 64) / block;   // 32768
            gather_kernel<<<grid, block, 0, stream>>>(features, cnt, list, out);
        }
        // fold overflow points (expected count: 0)
        ovf_kernel<<<1, 256, 0, stream>>>(features, coors, ovf_cnt, ovf, out);
    } else {
        // fallback: R1 atomic scatter path
        unsigned* acc = (unsigned*)d_out;
        init_kernel<<<2048, 256, 0, stream>>>((uint4*)d_out, OUT_ELEMS / 4);
        int grid = (n_pts * 64 + 255) / 256;
        scatter_kernel<<<grid, 256, 0, stream>>>(features, coors, acc, n_pts);
        finalize_kernel<<<2048, 256, 0, stream>>>(acc, OUT_ELEMS);
    }
}